// Round 1
// baseline (174.215 us; speedup 1.0000x reference)
//
#include <hip/hip_runtime.h>
#include <hip/hip_bf16.h>

#define B_  8
#define L_  4096
#define DM  65
#define DH  64

typedef __attribute__((ext_vector_type(8))) __bf16 bf16x8;
typedef __attribute__((ext_vector_type(4))) float  f32x4;
typedef __attribute__((ext_vector_type(8))) unsigned short u16x8;
typedef __attribute__((ext_vector_type(4))) unsigned short u16x4;

// ---------------------------------------------------------------------------
// Kernel 1: fused QKV projection.  x[32768,65] f32 -> q,k,v[32768,64] bf16.
// Q is pre-scaled by log2(e)/sqrt(65) so attention softmax can use exp2.
// ---------------------------------------------------------------------------
__global__ __launch_bounds__(256) void qkv_proj(
    const float* __restrict__ x,
    const float* __restrict__ Wq, const float* __restrict__ bq,
    const float* __restrict__ Wk, const float* __restrict__ bk,
    const float* __restrict__ Wv, const float* __restrict__ bv,
    unsigned short* __restrict__ qo,
    unsigned short* __restrict__ ko,
    unsigned short* __restrict__ vo)
{
    __shared__ float xs[128 * 65];
    __shared__ float wsm[65 * 64];
    __shared__ float bsm[64];

    const int tid = threadIdx.x;
    const long r0 = (long)blockIdx.x * 128;

    for (int i = tid; i < 128 * 65; i += 256) xs[i] = x[r0 * 65 + i];

    const float* Wp[3] = {Wq, Wk, Wv};
    const float* bp[3] = {bq, bk, bv};
    unsigned short* op[3] = {qo, ko, vo};

    const int rl = tid >> 1;          // local row 0..127
    const int c0 = (tid & 1) * 32;    // col half

    for (int p = 0; p < 3; ++p) {
        __syncthreads();
        for (int i = tid; i < 65 * 64; i += 256) wsm[i] = Wp[p][i];
        if (tid < 64) bsm[tid] = bp[p][tid];
        __syncthreads();

        float acc[32];
#pragma unroll
        for (int j = 0; j < 32; ++j) acc[j] = bsm[c0 + j];

        for (int d = 0; d < 65; ++d) {
            const float xv = xs[rl * 65 + d];
            const float4* wr = (const float4*)&wsm[d * 64 + c0];
#pragma unroll
            for (int j4 = 0; j4 < 8; ++j4) {
                float4 w = wr[j4];
                acc[j4 * 4 + 0] += xv * w.x;
                acc[j4 * 4 + 1] += xv * w.y;
                acc[j4 * 4 + 2] += xv * w.z;
                acc[j4 * 4 + 3] += xv * w.w;
            }
        }

        const float scale = (p == 0) ? (1.4426950408889634f / 8.06225774829855f)
                                     : 1.0f;
        unsigned short* outp = op[p] + (size_t)(r0 + rl) * DH + c0;
#pragma unroll
        for (int j = 0; j < 32; ++j) {
            float v = acc[j] * scale;
            __hip_bfloat16 h = __float2bfloat16(v);
            outp[j] = *reinterpret_cast<unsigned short*>(&h);
        }
    }
}

// ---------------------------------------------------------------------------
// Kernel 2: causal flash attention, bf16 MFMA 16x16x32.
// Block = (batch, 64 q rows), 4 waves x 16 q rows each. KV tiles of 32.
// S^T = K * Q^T trick puts P at q = lane&15 -> feeds PV A-operand directly.
// ---------------------------------------------------------------------------
__global__ __launch_bounds__(256) void attn(
    const unsigned short* __restrict__ Q,
    const unsigned short* __restrict__ K,
    const unsigned short* __restrict__ V,
    float* __restrict__ O)
{
    __shared__ __align__(16) unsigned short Kls[32 * 72]; // row-major, pad 64->72
    __shared__ __align__(16) unsigned short Vt[64 * 36];  // V^T, pad 32->36

    const int tid  = threadIdx.x;
    const int lane = tid & 63;
    const int wv   = tid >> 6;
    const int b    = blockIdx.x & 7;
    const int qb   = 63 - (blockIdx.x >> 3);   // heavy q-blocks dispatched first
    const int q0blk = qb * 64;
    const int q0w   = q0blk + wv * 16;
    const int lg = lane >> 4;    // lane group 0..3
    const int li = lane & 15;

    const size_t base = (size_t)b * L_ * DH;

    // Q fragments (held in registers for all tiles). k-slot: d = 8*lg + j.
    const int qr = q0w + li;
    const bf16x8 qf0 = __builtin_bit_cast(bf16x8,
        *(const u16x8*)(Q + base + (size_t)qr * DH + 8 * lg));
    const bf16x8 qf1 = __builtin_bit_cast(bf16x8,
        *(const u16x8*)(Q + base + (size_t)qr * DH + 32 + 8 * lg));

    f32x4 o[4] = {{0,0,0,0},{0,0,0,0},{0,0,0,0},{0,0,0,0}};
    float m    = -1e30f;
    float lsum = 0.0f;

    const int nt = 2 * qb + 2;
    const int sr = tid >> 3;          // staging row 0..31
    const int sc = (tid & 7) * 8;     // staging col 0..56

    for (int t = 0; t < nt; ++t) {
        const int kvb = t * 32;
        __syncthreads();
        // ---- stage K (row-major, padded) and V^T ----
        {
            const u16x8 k8 = *(const u16x8*)(K + base + (size_t)(kvb + sr) * DH + sc);
            *(u16x8*)&Kls[sr * 72 + sc] = k8;
            const u16x8 v8 = *(const u16x8*)(V + base + (size_t)(kvb + sr) * DH + sc);
#pragma unroll
            for (int i = 0; i < 8; ++i) Vt[(sc + i) * 36 + sr] = v8[i];
        }
        __syncthreads();

        if (kvb > q0w + 15) continue;   // tile fully masked for this wave

        // ---- S^T = K * Q^T : 4 MFMAs ----
        f32x4 s0 = {0,0,0,0}, s1 = {0,0,0,0};
        {
            bf16x8 kf;
            kf = __builtin_bit_cast(bf16x8, *(const u16x8*)&Kls[li * 72 + 8 * lg]);
            s0 = __builtin_amdgcn_mfma_f32_16x16x32_bf16(kf, qf0, s0, 0, 0, 0);
            kf = __builtin_bit_cast(bf16x8, *(const u16x8*)&Kls[li * 72 + 32 + 8 * lg]);
            s0 = __builtin_amdgcn_mfma_f32_16x16x32_bf16(kf, qf1, s0, 0, 0, 0);
            kf = __builtin_bit_cast(bf16x8, *(const u16x8*)&Kls[(16 + li) * 72 + 8 * lg]);
            s1 = __builtin_amdgcn_mfma_f32_16x16x32_bf16(kf, qf0, s1, 0, 0, 0);
            kf = __builtin_bit_cast(bf16x8, *(const u16x8*)&Kls[(16 + li) * 72 + 32 + 8 * lg]);
            s1 = __builtin_amdgcn_mfma_f32_16x16x32_bf16(kf, qf1, s1, 0, 0, 0);
        }

        // lane holds S^T for q = q0w+li at kv = kvb + 4*lg + r (s0) / +16 (s1)
        const int q = q0w + li;
        float sv[8];
#pragma unroll
        for (int r = 0; r < 4; ++r) { sv[r] = s0[r]; sv[4 + r] = s1[r]; }

        if (kvb + 31 > q0w) {   // causal mask needed in this tile
#pragma unroll
            for (int r = 0; r < 4; ++r) {
                sv[r]     = (kvb +      4 * lg + r > q) ? -1e30f : sv[r];
                sv[4 + r] = (kvb + 16 + 4 * lg + r > q) ? -1e30f : sv[4 + r];
            }
        }

        // ---- online softmax (scores already in log2 scale) ----
        float tm = sv[0];
#pragma unroll
        for (int i = 1; i < 8; ++i) tm = fmaxf(tm, sv[i]);
        tm = fmaxf(tm, __shfl_xor(tm, 16));
        tm = fmaxf(tm, __shfl_xor(tm, 32));
        const float mn = fmaxf(m, tm);
        const float alpha = __builtin_amdgcn_exp2f(m - mn);
        m = mn;

        float ps = 0.0f;
#pragma unroll
        for (int i = 0; i < 8; ++i) {
            const float pe = __builtin_amdgcn_exp2f(sv[i] - mn);
            sv[i] = pe;
            ps += pe;
        }
        ps += __shfl_xor(ps, 16);
        ps += __shfl_xor(ps, 32);
        lsum = lsum * alpha + ps;

        // rescale O accumulators (C/D row = 4*lg + r needs alpha of that q row)
#pragma unroll
        for (int r = 0; r < 4; ++r) {
            const float ar = __shfl(alpha, 4 * lg + r);
            o[0][r] *= ar; o[1][r] *= ar; o[2][r] *= ar; o[3][r] *= ar;
        }

        // P fragment: slot j -> kv = 4*lg + (j&3) + 16*(j>>2)
        bf16x8 pf;
#pragma unroll
        for (int i = 0; i < 8; ++i) pf[i] = (__bf16)sv[i];

        // ---- PV: 4 MFMAs over dv tiles, V frag uses the same kv bijection ----
#pragma unroll
        for (int tt = 0; tt < 4; ++tt) {
            const int dvr = tt * 16 + li;
            const u16x4 vlo = *(const u16x4*)&Vt[dvr * 36 + 4 * lg];
            const u16x4 vhi = *(const u16x4*)&Vt[dvr * 36 + 16 + 4 * lg];
            u16x8 vc;
#pragma unroll
            for (int i = 0; i < 4; ++i) { vc[i] = vlo[i]; vc[4 + i] = vhi[i]; }
            const bf16x8 vf = __builtin_bit_cast(bf16x8, vc);
            o[tt] = __builtin_amdgcn_mfma_f32_16x16x32_bf16(pf, vf, o[tt], 0, 0, 0);
        }
    }

    // ---- epilogue: divide by row sum, store f32 ----
    const float inv = 1.0f / lsum;   // valid for q = q0w + li
#pragma unroll
    for (int r = 0; r < 4; ++r) {
        const float ir = __shfl(inv, 4 * lg + r);
        float* orow = O + base + (size_t)(q0w + 4 * lg + r) * DH + li;
        orow[0]  = o[0][r] * ir;
        orow[16] = o[1][r] * ir;
        orow[32] = o[2][r] * ir;
        orow[48] = o[3][r] * ir;
    }
}

// ---------------------------------------------------------------------------
extern "C" void kernel_launch(void* const* d_in, const int* in_sizes, int n_in,
                              void* d_out, int out_size, void* d_ws, size_t ws_size,
                              hipStream_t stream)
{
    const float* x  = (const float*)d_in[0];
    const float* Wq = (const float*)d_in[1];
    const float* bq = (const float*)d_in[2];
    const float* Wk = (const float*)d_in[3];
    const float* bk = (const float*)d_in[4];
    const float* Wv = (const float*)d_in[5];
    const float* bv = (const float*)d_in[6];

    unsigned short* qw = (unsigned short*)d_ws;
    unsigned short* kw = qw + (size_t)B_ * L_ * DH;
    unsigned short* vw = kw + (size_t)B_ * L_ * DH;

    qkv_proj<<<256, 256, 0, stream>>>(x, Wq, bq, Wk, bk, Wv, bv, qw, kw, vw);
    attn<<<512, 256, 0, stream>>>(qw, kw, vw, (float*)d_out);
}